// Round 10
// baseline (224.189 us; speedup 1.0000x reference)
//
#include <hip/hip_runtime.h>
#include <math.h>

#define N_NODES  100000
#define N_EDGES  800000
#define F        64
#define N_GRAPHS 64
#define NPB      32          // nodes per block (2 waves x 16)

typedef _Float16 half8 __attribute__((ext_vector_type(8)));
typedef float    f32x4 __attribute__((ext_vector_type(4)));

// ---------------- workspace layout (bytes) ----------------
#define OFF_BUFA 0u           // ushort[N*F] 12,800,000 (xs / hs ping; rank aliases head)
#define OFF_BUFB 12800000u    // ushort[N*F] 12,800,000
#define OFF_DIS  25600000u    // float[N]       400,000
#define OFF_DEG  26000000u    // int[N]         400,000
#define OFF_ROWP 26400000u    // int[N+1]       400,004 (pad to 64)
#define OFF_COL  26800064u    // int[E]       3,200,000
#define OFF_BSUM 30000064u    // int[128]
#define OFF_WT   30000576u    // _Float16[3*4096] 24,576
// total ~30.0 MB

__device__ inline ushort f2bf(float f) {               // round-to-nearest-even
    uint u = __float_as_uint(f);
    u = (u + 0x7FFFu + ((u >> 16) & 1u)) >> 16;
    return (ushort)u;
}
__device__ inline float bf2f(ushort s) {
    return __uint_as_float(((uint)s) << 16);
}

__global__ void k_zero(int* __restrict__ p, int n) {
    int i = blockIdx.x * blockDim.x + threadIdx.x;
    if (i < n) p[i] = 0;
}

// degree count AND per-edge rank (return value of the atomic we already pay)
__global__ void k_degree(const int* __restrict__ dst, int* __restrict__ degcnt,
                         int* __restrict__ rank) {
    int e = blockIdx.x * blockDim.x + threadIdx.x;
    if (e < N_EDGES) rank[e] = atomicAdd(&degcnt[dst[e]], 1);
}

// block scan of degcnt -> rowptr[i+1]; block totals -> bsum; dis fused.
__global__ void k_scan1(const int* __restrict__ degcnt, int* __restrict__ rowptr,
                        int* __restrict__ bsum, float* __restrict__ dis) {
    __shared__ int s[1024];
    int i = blockIdx.x * 1024 + threadIdx.x;
    int v = (i < N_NODES) ? degcnt[i] : 0;
    if (i < N_NODES) dis[i] = rsqrtf((float)v + 1.0f);
    s[threadIdx.x] = v;
    __syncthreads();
    for (int off = 1; off < 1024; off <<= 1) {
        int t = (threadIdx.x >= off) ? s[threadIdx.x - off] : 0;
        __syncthreads();
        s[threadIdx.x] += t;
        __syncthreads();
    }
    if (i < N_NODES) rowptr[i + 1] = s[threadIdx.x];
    if (threadIdx.x == 1023) bsum[blockIdx.x] = s[1023];
}

// parallel exclusive scan of the 98 block sums
__global__ void k_scan2(int* __restrict__ bsum, int nb) {
    __shared__ int s[128];
    int t = threadIdx.x;
    int v = (t < nb) ? bsum[t] : 0;
    s[t] = v;
    __syncthreads();
    for (int off = 1; off < 128; off <<= 1) {
        int u = (t >= off) ? s[t - off] : 0;
        __syncthreads();
        s[t] += u;
        __syncthreads();
    }
    if (t < nb) bsum[t] = s[t] - v;   // exclusive
}

__global__ void k_scan3(int* __restrict__ rowptr, const int* __restrict__ bsum) {
    int i = blockIdx.x * 1024 + threadIdx.x;
    if (i < N_NODES) rowptr[i + 1] += bsum[blockIdx.x];
    if (i == 0) rowptr[0] = 0;
}

// no atomics: position comes from rowptr + precomputed rank
__global__ void k_fill(const int* __restrict__ src, const int* __restrict__ dst,
                       const int* __restrict__ rowptr, const int* __restrict__ rank,
                       int* __restrict__ col) {
    int e = blockIdx.x * blockDim.x + threadIdx.x;
    if (e < N_EDGES) {
        int d = dst[e];
        col[rowptr[d] + rank[e]] = src[e];
    }
}

// xs = bf16(dis * x)  (layer-1 gather source; 8 elems/thread)
__global__ void k_prepx(const float* __restrict__ x, const float* __restrict__ dis,
                        ushort* __restrict__ xs) {
    int t = blockIdx.x * blockDim.x + threadIdx.x;
    if (t < N_NODES * 8) {
        int n = t >> 3;
        float d = dis[n];
        const float4* px = (const float4*)(x + (size_t)t * 8);
        float4 a = px[0], b = px[1];
        ushort o[8] = { f2bf(d*a.x), f2bf(d*a.y), f2bf(d*a.z), f2bf(d*a.w),
                        f2bf(d*b.x), f2bf(d*b.y), f2bf(d*b.z), f2bf(d*b.w) };
        *(uint4*)(xs + (size_t)t * 8) = *(const uint4*)o;
    }
}

// Wt[w][f][k] = f16(W_w[k][f])  — transposed f16 weights for MFMA B-fragments
__global__ void k_prepw(const float* __restrict__ W1, const float* __restrict__ W2,
                        const float* __restrict__ W3, _Float16* __restrict__ Wt) {
    int t = blockIdx.x * blockDim.x + threadIdx.x;
    if (t < 3 * 4096) {
        int wsel = t >> 12, i = t & 4095;
        int k = i >> 6, f = i & 63;
        const float* Ws = (wsel == 0) ? W1 : (wsel == 1) ? W2 : W3;
        Wt[wsel * 4096 + f * 64 + k] = (_Float16)Ws[k * 64 + f];
    }
}

// Fused GCN layer (agg-first, barrier-free):
//   g[n] = dis[n]*( hs[n] + sum_{e:dst=n} hs[src] )   (hs pre-scaled by dis; f16 LDS)
//   h'   = relu( g[n]·W + b );  out = bf16( SCALE ? dis*h' : h' )
// Block = 32 nodes, 2 waves (grid 3125 -> ~12 blocks/CU: occupancy no longer
// grid-starved). Wave owns rows [16w,16w+16); all 17 row bounds staged once
// (one vector load + readlane). Per quad: unmasked joint loop (16 gathers in
// flight) then MASKED joint tail — all 4 nodes keep issuing 4 clamped gathers
// (dup-line loads ~free, addends zeroed) so MLP stays 16 to the end.
// Phase2 MFMA reads only the wave's own LDS strip; epilogue stores direct to
// global (C/D layout col=lane&15, row=(lane>>4)*4+reg). No barriers anywhere.
template<bool RELU, bool SCALE>
__global__ __launch_bounds__(128) void k_layer(const ushort* __restrict__ hs,
                                               const int* __restrict__ rowptr,
                                               const int* __restrict__ col,
                                               const float* __restrict__ dis,
                                               const _Float16* __restrict__ Wt,
                                               const float* __restrict__ bias,
                                               ushort* __restrict__ hout) {
    __shared__ _Float16 g[NPB * 64];
    int lane = threadIdx.x & 63;
    int w    = __builtin_amdgcn_readfirstlane(threadIdx.x >> 6);
    int chunk = blockIdx.x * NPB;
    int wr16 = w * 16;
    int nbase = chunk + wr16;

    // stage the wave's 17 row bounds: vb lanes 0..15 = rowptr[nbase+1 .. nbase+16]
    int bidx = nbase + 1 + (lane & 15);
    int vb = rowptr[bidx <= N_NODES ? bidx : N_NODES];
    int w0i = nbase <= N_NODES ? nbase : N_NODES;
    int we0 = __builtin_amdgcn_readfirstlane(rowptr[w0i]);

    // ---------- phase 1: aggregate 16 nodes (4 quads x 4 nodes) ----------
#pragma unroll
    for (int p = 0; p < 4; ++p) {
        int na = nbase + 4 * p;
        int rowb = wr16 + 4 * p;
        int q0 = (p == 0) ? we0 : __builtin_amdgcn_readlane(vb, 4 * p - 1);
        int q1 = __builtin_amdgcn_readlane(vb, 4 * p);
        int q2 = __builtin_amdgcn_readlane(vb, 4 * p + 1);
        int q3 = __builtin_amdgcn_readlane(vb, 4 * p + 2);
        int q4 = __builtin_amdgcn_readlane(vb, 4 * p + 3);
        // self-loop init (invalid nodes have empty ranges and acc=0)
        float a0 = (na     < N_NODES) ? bf2f(hs[(size_t)na      * F + lane]) : 0.f;
        float a1 = (na + 1 < N_NODES) ? bf2f(hs[(size_t)(na + 1) * F + lane]) : 0.f;
        float a2 = (na + 2 < N_NODES) ? bf2f(hs[(size_t)(na + 2) * F + lane]) : 0.f;
        float a3 = (na + 3 < N_NODES) ? bf2f(hs[(size_t)(na + 3) * F + lane]) : 0.f;
        int ea = q0, eb = q1, ec = q2, ed = q3;
        // unmasked joint loop: 16 independent gathers in flight
        while (ea + 3 < q1 && eb + 3 < q2 && ec + 3 < q3 && ed + 3 < q4) {
            int sa0 = col[ea], sa1 = col[ea+1], sa2 = col[ea+2], sa3 = col[ea+3];
            int sb0 = col[eb], sb1 = col[eb+1], sb2 = col[eb+2], sb3 = col[eb+3];
            int sc0 = col[ec], sc1 = col[ec+1], sc2 = col[ec+2], sc3 = col[ec+3];
            int sd0 = col[ed], sd1 = col[ed+1], sd2 = col[ed+2], sd3 = col[ed+3];
            float va0 = bf2f(hs[(size_t)sa0 * F + lane]);
            float va1 = bf2f(hs[(size_t)sa1 * F + lane]);
            float va2 = bf2f(hs[(size_t)sa2 * F + lane]);
            float va3 = bf2f(hs[(size_t)sa3 * F + lane]);
            float vb0 = bf2f(hs[(size_t)sb0 * F + lane]);
            float vb1 = bf2f(hs[(size_t)sb1 * F + lane]);
            float vb2 = bf2f(hs[(size_t)sb2 * F + lane]);
            float vb3 = bf2f(hs[(size_t)sb3 * F + lane]);
            float vc0 = bf2f(hs[(size_t)sc0 * F + lane]);
            float vc1 = bf2f(hs[(size_t)sc1 * F + lane]);
            float vc2 = bf2f(hs[(size_t)sc2 * F + lane]);
            float vc3 = bf2f(hs[(size_t)sc3 * F + lane]);
            float vd0 = bf2f(hs[(size_t)sd0 * F + lane]);
            float vd1 = bf2f(hs[(size_t)sd1 * F + lane]);
            float vd2 = bf2f(hs[(size_t)sd2 * F + lane]);
            float vd3 = bf2f(hs[(size_t)sd3 * F + lane]);
            a0 += va0 + va1 + va2 + va3;
            a1 += vb0 + vb1 + vb2 + vb3;
            a2 += vc0 + vc1 + vc2 + vc3;
            a3 += vd0 + vd1 + vd2 + vd3;
            ea += 4; eb += 4; ec += 4; ed += 4;
        }
        // masked joint tail: keep 16 gathers in flight; clamped dup loads are
        // line-hits, addends zeroed by predicate.
        while (ea < q1 || eb < q2 || ec < q3 || ed < q4) {
            int ca = (q0 < q1) ? q1 - 1 : 0;   // safe clamp targets
            int cb = (q1 < q2) ? q2 - 1 : 0;
            int cc = (q2 < q3) ? q3 - 1 : 0;
            int cd = (q3 < q4) ? q4 - 1 : 0;
            int xa0 = min(ea,     ca), xa1 = min(ea + 1, ca), xa2 = min(ea + 2, ca), xa3 = min(ea + 3, ca);
            int xb0 = min(eb,     cb), xb1 = min(eb + 1, cb), xb2 = min(eb + 2, cb), xb3 = min(eb + 3, cb);
            int xc0 = min(ec,     cc), xc1 = min(ec + 1, cc), xc2 = min(ec + 2, cc), xc3 = min(ec + 3, cc);
            int xd0 = min(ed,     cd), xd1 = min(ed + 1, cd), xd2 = min(ed + 2, cd), xd3 = min(ed + 3, cd);
            int sa0 = col[xa0], sa1 = col[xa1], sa2 = col[xa2], sa3 = col[xa3];
            int sb0 = col[xb0], sb1 = col[xb1], sb2 = col[xb2], sb3 = col[xb3];
            int sc0 = col[xc0], sc1 = col[xc1], sc2 = col[xc2], sc3 = col[xc3];
            int sd0 = col[xd0], sd1 = col[xd1], sd2 = col[xd2], sd3 = col[xd3];
            float va0 = bf2f(hs[(size_t)sa0 * F + lane]);
            float va1 = bf2f(hs[(size_t)sa1 * F + lane]);
            float va2 = bf2f(hs[(size_t)sa2 * F + lane]);
            float va3 = bf2f(hs[(size_t)sa3 * F + lane]);
            float vb0 = bf2f(hs[(size_t)sb0 * F + lane]);
            float vb1 = bf2f(hs[(size_t)sb1 * F + lane]);
            float vb2 = bf2f(hs[(size_t)sb2 * F + lane]);
            float vb3 = bf2f(hs[(size_t)sb3 * F + lane]);
            float vc0 = bf2f(hs[(size_t)sc0 * F + lane]);
            float vc1 = bf2f(hs[(size_t)sc1 * F + lane]);
            float vc2 = bf2f(hs[(size_t)sc2 * F + lane]);
            float vc3 = bf2f(hs[(size_t)sc3 * F + lane]);
            float vd0 = bf2f(hs[(size_t)sd0 * F + lane]);
            float vd1 = bf2f(hs[(size_t)sd1 * F + lane]);
            float vd2 = bf2f(hs[(size_t)sd2 * F + lane]);
            float vd3 = bf2f(hs[(size_t)sd3 * F + lane]);
            a0 += ((ea     < q1) ? va0 : 0.f) + ((ea + 1 < q1) ? va1 : 0.f)
                + ((ea + 2 < q1) ? va2 : 0.f) + ((ea + 3 < q1) ? va3 : 0.f);
            a1 += ((eb     < q2) ? vb0 : 0.f) + ((eb + 1 < q2) ? vb1 : 0.f)
                + ((eb + 2 < q2) ? vb2 : 0.f) + ((eb + 3 < q2) ? vb3 : 0.f);
            a2 += ((ec     < q3) ? vc0 : 0.f) + ((ec + 1 < q3) ? vc1 : 0.f)
                + ((ec + 2 < q3) ? vc2 : 0.f) + ((ec + 3 < q3) ? vc3 : 0.f);
            a3 += ((ed     < q4) ? vd0 : 0.f) + ((ed + 1 < q4) ? vd1 : 0.f)
                + ((ed + 2 < q4) ? vd2 : 0.f) + ((ed + 3 < q4) ? vd3 : 0.f);
            ea = min(ea + 4, q1); eb = min(eb + 4, q2);
            ec = min(ec + 4, q3); ed = min(ed + 4, q4);
        }
        // fold dis and store f16 rows (own strip only)
        float d0 = (na     < N_NODES) ? dis[na]     : 0.f;
        float d1 = (na + 1 < N_NODES) ? dis[na + 1] : 0.f;
        float d2 = (na + 2 < N_NODES) ? dis[na + 2] : 0.f;
        float d3 = (na + 3 < N_NODES) ? dis[na + 3] : 0.f;
        g[(rowb    ) * 64 + lane] = (_Float16)(d0 * a0);
        g[(rowb + 1) * 64 + lane] = (_Float16)(d1 * a1);
        g[(rowb + 2) * 64 + lane] = (_Float16)(d2 * a2);
        g[(rowb + 3) * 64 + lane] = (_Float16)(d3 * a3);
    }
    // no barrier: phase 2 reads only this wave's own strip (same-wave LDS ordering)

    // ---------- phase 2: C[16x64] = g_strip · W via MFMA ----------
    int l15 = lane & 15, lh = lane >> 4;
    half8 bfrag[2][4];
#pragma unroll
    for (int ks = 0; ks < 2; ++ks)
#pragma unroll
        for (int nt = 0; nt < 4; ++nt)
            bfrag[ks][nt] = *(const half8*)(Wt + (nt * 16 + l15) * 64 + ks * 32 + lh * 8);

    f32x4 acc4[4] = {};
#pragma unroll
    for (int ks = 0; ks < 2; ++ks) {
        half8 a = *(const half8*)(&g[(wr16 + l15) * 64 + ks * 32 + lh * 8]);
#pragma unroll
        for (int nt = 0; nt < 4; ++nt)
            acc4[nt] = __builtin_amdgcn_mfma_f32_16x16x32_f16(a, bfrag[ks][nt], acc4[nt], 0, 0, 0);
    }

    // ---------- epilogue: direct global stores (no LDS, no barrier) ----------
    float bvals[4];
#pragma unroll
    for (int nt = 0; nt < 4; ++nt) bvals[nt] = bias[nt * 16 + l15];
#pragma unroll
    for (int rr = 0; rr < 4; ++rr) {
        int row = wr16 + lh * 4 + rr;
        int ng = chunk + row;
        if (ng < N_NODES) {
            float ds2 = 1.f;
            if (SCALE) ds2 = dis[ng];
#pragma unroll
            for (int nt = 0; nt < 4; ++nt) {
                float vv = acc4[nt][rr] + bvals[nt];
                if (RELU) vv = fmaxf(vv, 0.f);
                if (SCALE) vv *= ds2;
                hout[(size_t)ng * F + nt * 16 + l15] = f2bf(vv);
            }
        }
    }
}

__global__ void k_pool_init(float* __restrict__ out) {
    int i = blockIdx.x * blockDim.x + threadIdx.x;
    if (i < N_GRAPHS * F) out[i] = -INFINITY;
}

__device__ inline void atomicMaxFloat(float* addr, float v) {
    if (v >= 0.f) atomicMax((int*)addr, __float_as_int(v));
    else          atomicMin((unsigned int*)addr, __float_as_uint(v));
}

// batch is sorted: each wave scans a contiguous chunk, flushes on boundary.
__global__ __launch_bounds__(256) void k_pool(const ushort* __restrict__ h,
                                              const int* __restrict__ batch,
                                              float* __restrict__ out) {
    int lane = threadIdx.x & 63;
    int wid  = __builtin_amdgcn_readfirstlane((blockIdx.x * blockDim.x + threadIdx.x) >> 6);
    int nwaves = (gridDim.x * blockDim.x) >> 6;
    int per = (N_NODES + nwaves - 1) / nwaves;
    int n0 = wid * per, n1 = min(N_NODES, n0 + per);
    if (n0 >= n1) return;
    float acc = -INFINITY;
    int cur = batch[n0];
    for (int n = n0; n < n1; ++n) {
        int g = batch[n];
        if (g != cur) {
            atomicMaxFloat(&out[cur * F + lane], acc);
            acc = -INFINITY; cur = g;
        }
        acc = fmaxf(acc, bf2f(h[(size_t)n * F + lane]));
    }
    atomicMaxFloat(&out[cur * F + lane], acc);
}

extern "C" void kernel_launch(void* const* d_in, const int* in_sizes, int n_in,
                              void* d_out, int out_size, void* d_ws, size_t ws_size,
                              hipStream_t stream) {
    const float* x     = (const float*)d_in[0];
    const int*   ei    = (const int*)d_in[1];
    const int*   batch = (const int*)d_in[2];
    const float* W1 = (const float*)d_in[3];
    const float* b1 = (const float*)d_in[4];
    const float* W2 = (const float*)d_in[5];
    const float* b2 = (const float*)d_in[6];
    const float* W3 = (const float*)d_in[7];
    const float* b3 = (const float*)d_in[8];
    const int* src = ei;
    const int* dst = ei + N_EDGES;

    char* ws = (char*)d_ws;
    ushort*   bufA   = (ushort*)(ws + OFF_BUFA);
    int*      rank   = (int*)(ws + OFF_BUFA);     // alias: live only during CSR build
    ushort*   bufB   = (ushort*)(ws + OFF_BUFB);
    float*    dis    = (float*)(ws + OFF_DIS);
    int*      degcnt = (int*)(ws + OFF_DEG);
    int*      rowptr = (int*)(ws + OFF_ROWP);
    int*      col    = (int*)(ws + OFF_COL);
    int*      bsum   = (int*)(ws + OFF_BSUM);
    _Float16* wt     = (_Float16*)(ws + OFF_WT);
    float*    out    = (float*)d_out;

    // CSR build
    k_zero<<<(N_NODES + 255) / 256, 256, 0, stream>>>(degcnt, N_NODES);
    k_degree<<<(N_EDGES + 255) / 256, 256, 0, stream>>>(dst, degcnt, rank);
    k_scan1<<<98, 1024, 0, stream>>>(degcnt, rowptr, bsum, dis);
    k_scan2<<<1, 128, 0, stream>>>(bsum, 98);
    k_scan3<<<98, 1024, 0, stream>>>(rowptr, bsum);
    k_fill<<<(N_EDGES + 255) / 256, 256, 0, stream>>>(src, dst, rowptr, rank, col);

    // prep: xs = bf16(dis*x) (overwrites rank region), Wt = f16 transposed weights
    k_prepx<<<(N_NODES * 8 + 255) / 256, 256, 0, stream>>>(x, dis, bufA);
    k_prepw<<<48, 256, 0, stream>>>(W1, W2, W3, wt);

    const int LBLOCKS = (N_NODES + NPB - 1) / NPB;   // 3125
    k_layer<true,  true ><<<LBLOCKS, 128, 0, stream>>>(bufA, rowptr, col, dis, wt,        b1, bufB);
    k_layer<true,  true ><<<LBLOCKS, 128, 0, stream>>>(bufB, rowptr, col, dis, wt + 4096, b2, bufA);
    k_layer<false, false><<<LBLOCKS, 128, 0, stream>>>(bufA, rowptr, col, dis, wt + 8192, b3, bufB);

    // global max pool
    k_pool_init<<<(N_GRAPHS * F + 255) / 256, 256, 0, stream>>>(out);
    k_pool<<<512, 256, 0, stream>>>(bufB, batch, out);
}

// Round 11
// 186.984 us; speedup vs baseline: 1.1990x; 1.1990x over previous
//
#include <hip/hip_runtime.h>
#include <math.h>

#define N_NODES  100000
#define N_EDGES  800000
#define F        64
#define N_GRAPHS 64
#define NQUADS   25000       // N_NODES/4 exactly

typedef _Float16 half8 __attribute__((ext_vector_type(8)));
typedef float    f32x4 __attribute__((ext_vector_type(4)));

// ---------------- workspace layout (bytes) ----------------
#define OFF_BUFA 0u           // ushort[(N+1)*F] 12,800,128 (row N = zero sentinel; rank aliases head)
#define OFF_BUFB 12800256u    // ushort[(N+1)*F] 12,800,128
#define OFF_DIS  25600512u    // float[N]       400,000
#define OFF_DEG  26000512u    // int[N]         400,000
#define OFF_QB   26400512u    // int[NQUADS+1]  100,004 (quad-padded CSR base, 16-int aligned entries)
#define OFF_BSUM 26500544u    // int[128]
#define OFF_COL  26501120u    // int[<=3.5M]  14,000,000 (padded+interleaved col, sentinel N_NODES)
#define OFF_WT   40501120u    // _Float16[3*4096] 24,576
// total ~40.5 MB

__device__ inline ushort f2bf(float f) {               // round-to-nearest-even
    uint u = __float_as_uint(f);
    u = (u + 0x7FFFu + ((u >> 16) & 1u)) >> 16;
    return (ushort)u;
}
__device__ inline float bf2f(ushort s) {
    return __uint_as_float(((uint)s) << 16);
}

__global__ void k_zero(int* __restrict__ p, int n) {
    int i = blockIdx.x * blockDim.x + threadIdx.x;
    if (i < n) p[i] = 0;
}

// degree count AND per-edge rank (return value of the atomic we already pay)
__global__ void k_degree(const int* __restrict__ dst, int* __restrict__ degcnt,
                         int* __restrict__ rank) {
    int e = blockIdx.x * blockDim.x + threadIdx.x;
    if (e < N_EDGES) rank[e] = atomicAdd(&degcnt[dst[e]], 1);
}

// per-QUAD kernel: dis for 4 nodes; padded quad slot count = 4*ceil(maxdeg/4);
// block-inclusive-scan -> qbase[q+1]; block totals -> bsum.
__global__ void k_quad(const int* __restrict__ degcnt, int* __restrict__ qbase,
                       int* __restrict__ bsum, float* __restrict__ dis) {
    __shared__ int s[1024];
    int q = blockIdx.x * 1024 + threadIdx.x;
    int tot = 0;
    if (q < NQUADS) {
        const int4 d4 = *(const int4*)(degcnt + q * 4);
        float4 dv;
        dv.x = rsqrtf((float)d4.x + 1.0f);
        dv.y = rsqrtf((float)d4.y + 1.0f);
        dv.z = rsqrtf((float)d4.z + 1.0f);
        dv.w = rsqrtf((float)d4.w + 1.0f);
        *(float4*)(dis + q * 4) = dv;
        int m = max(max(d4.x, d4.y), max(d4.z, d4.w));
        int P = (m + 3) & ~3;          // per-node padded length (multiple of 4)
        tot = 4 * P;                   // quad slots (multiple of 16 -> bases 16-aligned)
    }
    s[threadIdx.x] = tot;
    __syncthreads();
    for (int off = 1; off < 1024; off <<= 1) {
        int t = (threadIdx.x >= off) ? s[threadIdx.x - off] : 0;
        __syncthreads();
        s[threadIdx.x] += t;
        __syncthreads();
    }
    if (q < NQUADS) qbase[q + 1] = s[threadIdx.x];
    if (threadIdx.x == 1023) bsum[blockIdx.x] = s[1023];
}

// parallel exclusive scan of the block sums
__global__ void k_scan2(int* __restrict__ bsum, int nb) {
    __shared__ int s[128];
    int t = threadIdx.x;
    int v = (t < nb) ? bsum[t] : 0;
    s[t] = v;
    __syncthreads();
    for (int off = 1; off < 128; off <<= 1) {
        int u = (t >= off) ? s[t - off] : 0;
        __syncthreads();
        s[t] += u;
        __syncthreads();
    }
    if (t < nb) bsum[t] = s[t] - v;   // exclusive
}

__global__ void k_scan3(int* __restrict__ qbase, const int* __restrict__ bsum) {
    int q = blockIdx.x * 1024 + threadIdx.x;
    if (q < NQUADS) qbase[q + 1] += bsum[blockIdx.x];
    if (q == 0) qbase[0] = 0;
}

// sentinel-init the used prefix of col
__global__ void k_colinit(const int* __restrict__ qbase, int* __restrict__ col) {
    int total = qbase[NQUADS];
    int stride = gridDim.x * blockDim.x;
    for (int i = blockIdx.x * blockDim.x + threadIdx.x; i < total; i += stride)
        col[i] = N_NODES;
}

// interleaved padded fill: edge (src,dst,rank) -> col[qbase[dst/4] + rank*4 + (dst&3)]
__global__ void k_fill(const int* __restrict__ src, const int* __restrict__ dst,
                       const int* __restrict__ qbase, const int* __restrict__ rank,
                       int* __restrict__ col) {
    int e = blockIdx.x * blockDim.x + threadIdx.x;
    if (e < N_EDGES) {
        int d = dst[e];
        col[qbase[d >> 2] + rank[e] * 4 + (d & 3)] = src[e];
    }
}

// xs = bf16(dis * x)  (layer-1 gather source; 8 elems/thread)
__global__ void k_prepx(const float* __restrict__ x, const float* __restrict__ dis,
                        ushort* __restrict__ xs) {
    int t = blockIdx.x * blockDim.x + threadIdx.x;
    if (t < N_NODES * 8) {
        int n = t >> 3;
        float d = dis[n];
        const float4* px = (const float4*)(x + (size_t)t * 8);
        float4 a = px[0], b = px[1];
        ushort o[8] = { f2bf(d*a.x), f2bf(d*a.y), f2bf(d*a.z), f2bf(d*a.w),
                        f2bf(d*b.x), f2bf(d*b.y), f2bf(d*b.z), f2bf(d*b.w) };
        *(uint4*)(xs + (size_t)t * 8) = *(const uint4*)o;
    }
}

// Wt = f16 transposed weights; also zero the sentinel rows of both h buffers
__global__ void k_prepw(const float* __restrict__ W1, const float* __restrict__ W2,
                        const float* __restrict__ W3, _Float16* __restrict__ Wt,
                        ushort* __restrict__ bufA, ushort* __restrict__ bufB) {
    int t = blockIdx.x * blockDim.x + threadIdx.x;
    if (t < 3 * 4096) {
        int wsel = t >> 12, i = t & 4095;
        int k = i >> 6, f = i & 63;
        const float* Ws = (wsel == 0) ? W1 : (wsel == 1) ? W2 : W3;
        Wt[wsel * 4096 + f * 64 + k] = (_Float16)Ws[k * 64 + f];
    } else if (t < 3 * 4096 + 64) {
        int f = t - 3 * 4096;
        bufA[(size_t)N_NODES * F + f] = 0;
        bufB[(size_t)N_NODES * F + f] = 0;
    }
}

// Fused GCN layer (agg-first, barrier-free, padded-CSR):
//   g[n] = dis[n]*( hs[n] + sum_{e:dst=n} hs[src] )   (hs pre-scaled by dis; f16 LDS)
//   h'   = relu( g[n]·W + b );  out = bf16( SCALE ? dis*h' : h' )
// Block = 64 nodes, 4 waves; wave owns rows [16w,16w+16) = 4 quads.
// Phase1 per quad: iters = quadslots/16; each iteration = one s_load_dwordx16
// of 16 contiguous interleaved col indices + 16 independent gathers + pure adds.
// Sentinel slots point at zero row hs[N_NODES] (L1-hot). No drains, no masks.
// Phase2 MFMA reads only the wave's own LDS strip; epilogue stores direct to
// global (C/D layout col=lane&15, row=(lane>>4)*4+reg). No barriers anywhere.
template<bool RELU, bool SCALE>
__global__ __launch_bounds__(256) void k_layer(const ushort* __restrict__ hs,
                                               const int* __restrict__ qbase,
                                               const int* __restrict__ col,
                                               const float* __restrict__ dis,
                                               const _Float16* __restrict__ Wt,
                                               const float* __restrict__ bias,
                                               ushort* __restrict__ hout) {
    __shared__ _Float16 g[64 * 64];
    int lane = threadIdx.x & 63;
    int w    = __builtin_amdgcn_readfirstlane(threadIdx.x >> 6);
    int chunk = blockIdx.x * 64;
    int wr16 = w * 16;
    int nbase = chunk + wr16;

    // ---------- phase 1: aggregate 16 nodes (4 quads) ----------
    for (int p = 0; p < 4; ++p) {
        int na = nbase + 4 * p;              // first node of quad
        int quad = na >> 2;
        int rowb = wr16 + 4 * p;
        bool vq = quad < NQUADS;
        int qb0 = 0, iters = 0;
        if (vq) {
            qb0   = __builtin_amdgcn_readfirstlane(qbase[quad]);
            int qb1 = __builtin_amdgcn_readfirstlane(qbase[quad + 1]);
            iters = (qb1 - qb0) >> 4;
        }
        // self-loop init (tail nodes: zero)
        float a0 = vq ? bf2f(hs[(size_t)(na    ) * F + lane]) : 0.f;
        float a1 = vq ? bf2f(hs[(size_t)(na + 1) * F + lane]) : 0.f;
        float a2 = vq ? bf2f(hs[(size_t)(na + 2) * F + lane]) : 0.f;
        float a3 = vq ? bf2f(hs[(size_t)(na + 3) * F + lane]) : 0.f;
        const int* cp0 = col + qb0;
        for (int i = 0; i < iters; ++i) {
            const int* cp = cp0 + (i << 4);  // uniform addr -> s_load_dwordx16
            int s0 = cp[0],  s1 = cp[1],  s2 = cp[2],  s3 = cp[3];
            int s4 = cp[4],  s5 = cp[5],  s6 = cp[6],  s7 = cp[7];
            int s8 = cp[8],  s9 = cp[9],  s10 = cp[10], s11 = cp[11];
            int s12 = cp[12], s13 = cp[13], s14 = cp[14], s15 = cp[15];
            float v0  = bf2f(hs[(size_t)s0  * F + lane]);
            float v1  = bf2f(hs[(size_t)s1  * F + lane]);
            float v2  = bf2f(hs[(size_t)s2  * F + lane]);
            float v3  = bf2f(hs[(size_t)s3  * F + lane]);
            float v4  = bf2f(hs[(size_t)s4  * F + lane]);
            float v5  = bf2f(hs[(size_t)s5  * F + lane]);
            float v6  = bf2f(hs[(size_t)s6  * F + lane]);
            float v7  = bf2f(hs[(size_t)s7  * F + lane]);
            float v8  = bf2f(hs[(size_t)s8  * F + lane]);
            float v9  = bf2f(hs[(size_t)s9  * F + lane]);
            float v10 = bf2f(hs[(size_t)s10 * F + lane]);
            float v11 = bf2f(hs[(size_t)s11 * F + lane]);
            float v12 = bf2f(hs[(size_t)s12 * F + lane]);
            float v13 = bf2f(hs[(size_t)s13 * F + lane]);
            float v14 = bf2f(hs[(size_t)s14 * F + lane]);
            float v15 = bf2f(hs[(size_t)s15 * F + lane]);
            a0 += v0 + v4 + v8  + v12;       // interleave: node j at slots j,4+j,8+j,12+j
            a1 += v1 + v5 + v9  + v13;
            a2 += v2 + v6 + v10 + v14;
            a3 += v3 + v7 + v11 + v15;
        }
        // fold dis and store f16 rows (own strip only)
        float d0 = vq ? dis[na]     : 0.f;
        float d1 = vq ? dis[na + 1] : 0.f;
        float d2 = vq ? dis[na + 2] : 0.f;
        float d3 = vq ? dis[na + 3] : 0.f;
        g[(rowb    ) * 64 + lane] = (_Float16)(d0 * a0);
        g[(rowb + 1) * 64 + lane] = (_Float16)(d1 * a1);
        g[(rowb + 2) * 64 + lane] = (_Float16)(d2 * a2);
        g[(rowb + 3) * 64 + lane] = (_Float16)(d3 * a3);
    }
    // no barrier: phase 2 reads only this wave's own strip (same-wave LDS ordering)

    // ---------- phase 2: C[16x64] = g_strip · W via MFMA ----------
    int l15 = lane & 15, lh = lane >> 4;
    half8 bfrag[2][4];
#pragma unroll
    for (int ks = 0; ks < 2; ++ks)
#pragma unroll
        for (int nt = 0; nt < 4; ++nt)
            bfrag[ks][nt] = *(const half8*)(Wt + (nt * 16 + l15) * 64 + ks * 32 + lh * 8);

    f32x4 acc4[4] = {};
#pragma unroll
    for (int ks = 0; ks < 2; ++ks) {
        half8 a = *(const half8*)(&g[(wr16 + l15) * 64 + ks * 32 + lh * 8]);
#pragma unroll
        for (int nt = 0; nt < 4; ++nt)
            acc4[nt] = __builtin_amdgcn_mfma_f32_16x16x32_f16(a, bfrag[ks][nt], acc4[nt], 0, 0, 0);
    }

    // ---------- epilogue: direct global stores (no LDS, no barrier) ----------
    float bvals[4];
#pragma unroll
    for (int nt = 0; nt < 4; ++nt) bvals[nt] = bias[nt * 16 + l15];
#pragma unroll
    for (int rr = 0; rr < 4; ++rr) {
        int row = wr16 + lh * 4 + rr;
        int ng = chunk + row;
        if (ng < N_NODES) {
            float ds2 = 1.f;
            if (SCALE) ds2 = dis[ng];
#pragma unroll
            for (int nt = 0; nt < 4; ++nt) {
                float vv = acc4[nt][rr] + bvals[nt];
                if (RELU) vv = fmaxf(vv, 0.f);
                if (SCALE) vv *= ds2;
                hout[(size_t)ng * F + nt * 16 + l15] = f2bf(vv);
            }
        }
    }
}

__global__ void k_pool_init(float* __restrict__ out) {
    int i = blockIdx.x * blockDim.x + threadIdx.x;
    if (i < N_GRAPHS * F) out[i] = -INFINITY;
}

__device__ inline void atomicMaxFloat(float* addr, float v) {
    if (v >= 0.f) atomicMax((int*)addr, __float_as_int(v));
    else          atomicMin((unsigned int*)addr, __float_as_uint(v));
}

// batch is sorted: each wave scans a contiguous chunk, flushes on boundary.
__global__ __launch_bounds__(256) void k_pool(const ushort* __restrict__ h,
                                              const int* __restrict__ batch,
                                              float* __restrict__ out) {
    int lane = threadIdx.x & 63;
    int wid  = __builtin_amdgcn_readfirstlane((blockIdx.x * blockDim.x + threadIdx.x) >> 6);
    int nwaves = (gridDim.x * blockDim.x) >> 6;
    int per = (N_NODES + nwaves - 1) / nwaves;
    int n0 = wid * per, n1 = min(N_NODES, n0 + per);
    if (n0 >= n1) return;
    float acc = -INFINITY;
    int cur = batch[n0];
    for (int n = n0; n < n1; ++n) {
        int g = batch[n];
        if (g != cur) {
            atomicMaxFloat(&out[cur * F + lane], acc);
            acc = -INFINITY; cur = g;
        }
        acc = fmaxf(acc, bf2f(h[(size_t)n * F + lane]));
    }
    atomicMaxFloat(&out[cur * F + lane], acc);
}

extern "C" void kernel_launch(void* const* d_in, const int* in_sizes, int n_in,
                              void* d_out, int out_size, void* d_ws, size_t ws_size,
                              hipStream_t stream) {
    const float* x     = (const float*)d_in[0];
    const int*   ei    = (const int*)d_in[1];
    const int*   batch = (const int*)d_in[2];
    const float* W1 = (const float*)d_in[3];
    const float* b1 = (const float*)d_in[4];
    const float* W2 = (const float*)d_in[5];
    const float* b2 = (const float*)d_in[6];
    const float* W3 = (const float*)d_in[7];
    const float* b3 = (const float*)d_in[8];
    const int* src = ei;
    const int* dst = ei + N_EDGES;

    char* ws = (char*)d_ws;
    ushort*   bufA   = (ushort*)(ws + OFF_BUFA);
    int*      rank   = (int*)(ws + OFF_BUFA);     // alias: live only during CSR build
    ushort*   bufB   = (ushort*)(ws + OFF_BUFB);
    float*    dis    = (float*)(ws + OFF_DIS);
    int*      degcnt = (int*)(ws + OFF_DEG);
    int*      qbase  = (int*)(ws + OFF_QB);
    int*      bsum   = (int*)(ws + OFF_BSUM);
    int*      col    = (int*)(ws + OFF_COL);
    _Float16* wt     = (_Float16*)(ws + OFF_WT);
    float*    out    = (float*)d_out;

    // CSR build (quad-padded, interleaved)
    k_zero<<<(N_NODES + 255) / 256, 256, 0, stream>>>(degcnt, N_NODES);
    k_degree<<<(N_EDGES + 255) / 256, 256, 0, stream>>>(dst, degcnt, rank);
    k_quad<<<25, 1024, 0, stream>>>(degcnt, qbase, bsum, dis);
    k_scan2<<<1, 128, 0, stream>>>(bsum, 25);
    k_scan3<<<25, 1024, 0, stream>>>(qbase, bsum);
    k_colinit<<<1024, 256, 0, stream>>>(qbase, col);
    k_fill<<<(N_EDGES + 255) / 256, 256, 0, stream>>>(src, dst, qbase, rank, col);

    // prep: xs = bf16(dis*x) (overwrites rank region), Wt + sentinel-row zeroing
    k_prepx<<<(N_NODES * 8 + 255) / 256, 256, 0, stream>>>(x, dis, bufA);
    k_prepw<<<49, 256, 0, stream>>>(W1, W2, W3, wt, bufA, bufB);

    const int LBLOCKS = (N_NODES + 63) / 64;   // 1563
    k_layer<true,  true ><<<LBLOCKS, 256, 0, stream>>>(bufA, qbase, col, dis, wt,        b1, bufB);
    k_layer<true,  true ><<<LBLOCKS, 256, 0, stream>>>(bufB, qbase, col, dis, wt + 4096, b2, bufA);
    k_layer<false, false><<<LBLOCKS, 256, 0, stream>>>(bufA, qbase, col, dis, wt + 8192, b3, bufB);

    // global max pool
    k_pool_init<<<(N_GRAPHS * F + 255) / 256, 256, 0, stream>>>(out);
    k_pool<<<512, 256, 0, stream>>>(bufB, batch, out);
}

// Round 12
// 181.125 us; speedup vs baseline: 1.2378x; 1.0323x over previous
//
#include <hip/hip_runtime.h>
#include <math.h>

#define N_NODES  100000
#define N_EDGES  800000
#define F        64
#define N_GRAPHS 64
#define NQUADS   25000       // N_NODES/4 exactly
#define ROWB     128         // bytes per hs row (64 * bf16)

typedef _Float16 half8 __attribute__((ext_vector_type(8)));
typedef float    f32x4 __attribute__((ext_vector_type(4)));

// ---------------- workspace layout (bytes) ----------------
#define OFF_BUFA 0u           // ushort[(N+1)*F] 12,800,128 (row N = zero sentinel; rank aliases head)
#define OFF_BUFB 12800256u    // ushort[(N+1)*F] 12,800,128
#define OFF_DIS  25600512u    // float[N]       400,000
#define OFF_DEG  26000512u    // int[N]         400,000
#define OFF_QB   26400512u    // int[NQUADS+1]  100,004 (quad-padded CSR base, 16-int aligned entries)
#define OFF_BSUM 26500544u    // int[128]
#define OFF_COL  26501120u    // int[<=3.5M]  14,000,000 (padded+interleaved col, BYTE offsets)
#define OFF_WT   40501120u    // _Float16[3*4096] 24,576
// total ~40.5 MB

__device__ inline ushort f2bf(float f) {               // round-to-nearest-even
    uint u = __float_as_uint(f);
    u = (u + 0x7FFFu + ((u >> 16) & 1u)) >> 16;
    return (ushort)u;
}
__device__ inline float bf2f(ushort s) {
    return __uint_as_float(((uint)s) << 16);
}

__global__ void k_zero(int* __restrict__ p, int n) {
    int i = blockIdx.x * blockDim.x + threadIdx.x;
    if (i < n) p[i] = 0;
}

// degree count AND per-edge rank (return value of the atomic we already pay)
__global__ void k_degree(const int* __restrict__ dst, int* __restrict__ degcnt,
                         int* __restrict__ rank) {
    int e = blockIdx.x * blockDim.x + threadIdx.x;
    if (e < N_EDGES) rank[e] = atomicAdd(&degcnt[dst[e]], 1);
}

// per-QUAD kernel: dis for 4 nodes; padded quad slot count = 4*ceil(maxdeg/4);
// block-inclusive-scan -> qbase[q+1]; block totals -> bsum.
__global__ void k_quad(const int* __restrict__ degcnt, int* __restrict__ qbase,
                       int* __restrict__ bsum, float* __restrict__ dis) {
    __shared__ int s[1024];
    int q = blockIdx.x * 1024 + threadIdx.x;
    int tot = 0;
    if (q < NQUADS) {
        const int4 d4 = *(const int4*)(degcnt + q * 4);
        float4 dv;
        dv.x = rsqrtf((float)d4.x + 1.0f);
        dv.y = rsqrtf((float)d4.y + 1.0f);
        dv.z = rsqrtf((float)d4.z + 1.0f);
        dv.w = rsqrtf((float)d4.w + 1.0f);
        *(float4*)(dis + q * 4) = dv;
        int m = max(max(d4.x, d4.y), max(d4.z, d4.w));
        int P = (m + 3) & ~3;          // per-node padded length (multiple of 4)
        tot = 4 * P;                   // quad slots (multiple of 16 -> bases 16-aligned)
    }
    s[threadIdx.x] = tot;
    __syncthreads();
    for (int off = 1; off < 1024; off <<= 1) {
        int t = (threadIdx.x >= off) ? s[threadIdx.x - off] : 0;
        __syncthreads();
        s[threadIdx.x] += t;
        __syncthreads();
    }
    if (q < NQUADS) qbase[q + 1] = s[threadIdx.x];
    if (threadIdx.x == 1023) bsum[blockIdx.x] = s[1023];
}

// parallel exclusive scan of the block sums
__global__ void k_scan2(int* __restrict__ bsum, int nb) {
    __shared__ int s[128];
    int t = threadIdx.x;
    int v = (t < nb) ? bsum[t] : 0;
    s[t] = v;
    __syncthreads();
    for (int off = 1; off < 128; off <<= 1) {
        int u = (t >= off) ? s[t - off] : 0;
        __syncthreads();
        s[t] += u;
        __syncthreads();
    }
    if (t < nb) bsum[t] = s[t] - v;   // exclusive
}

__global__ void k_scan3(int* __restrict__ qbase, const int* __restrict__ bsum) {
    int q = blockIdx.x * 1024 + threadIdx.x;
    if (q < NQUADS) qbase[q + 1] += bsum[blockIdx.x];
    if (q == 0) qbase[0] = 0;
}

// sentinel-init the used prefix of col (sentinel = byte offset of zero row)
__global__ void k_colinit(const int* __restrict__ qbase, int* __restrict__ col) {
    int total = qbase[NQUADS];
    int stride = gridDim.x * blockDim.x;
    for (int i = blockIdx.x * blockDim.x + threadIdx.x; i < total; i += stride)
        col[i] = N_NODES * ROWB;
}

// interleaved padded fill with BYTE offsets:
// edge (src,dst,rank) -> col[qbase[dst/4] + rank*4 + (dst&3)] = src*ROWB
__global__ void k_fill(const int* __restrict__ src, const int* __restrict__ dst,
                       const int* __restrict__ qbase, const int* __restrict__ rank,
                       int* __restrict__ col) {
    int e = blockIdx.x * blockDim.x + threadIdx.x;
    if (e < N_EDGES) {
        int d = dst[e];
        col[qbase[d >> 2] + rank[e] * 4 + (d & 3)] = src[e] * ROWB;
    }
}

// xs = bf16(dis * x)  (layer-1 gather source; 8 elems/thread)
__global__ void k_prepx(const float* __restrict__ x, const float* __restrict__ dis,
                        ushort* __restrict__ xs) {
    int t = blockIdx.x * blockDim.x + threadIdx.x;
    if (t < N_NODES * 8) {
        int n = t >> 3;
        float d = dis[n];
        const float4* px = (const float4*)(x + (size_t)t * 8);
        float4 a = px[0], b = px[1];
        ushort o[8] = { f2bf(d*a.x), f2bf(d*a.y), f2bf(d*a.z), f2bf(d*a.w),
                        f2bf(d*b.x), f2bf(d*b.y), f2bf(d*b.z), f2bf(d*b.w) };
        *(uint4*)(xs + (size_t)t * 8) = *(const uint4*)o;
    }
}

// Wt = f16 transposed weights; zero sentinel rows; init pool output to -INF
__global__ void k_prepw(const float* __restrict__ W1, const float* __restrict__ W2,
                        const float* __restrict__ W3, _Float16* __restrict__ Wt,
                        ushort* __restrict__ bufA, ushort* __restrict__ bufB,
                        float* __restrict__ out) {
    int t = blockIdx.x * blockDim.x + threadIdx.x;
    if (t < 3 * 4096) {
        int wsel = t >> 12, i = t & 4095;
        int k = i >> 6, f = i & 63;
        const float* Ws = (wsel == 0) ? W1 : (wsel == 1) ? W2 : W3;
        Wt[wsel * 4096 + f * 64 + k] = (_Float16)Ws[k * 64 + f];
    } else if (t < 3 * 4096 + 64) {
        int f = t - 3 * 4096;
        bufA[(size_t)N_NODES * F + f] = 0;
        bufB[(size_t)N_NODES * F + f] = 0;
    } else if (t < 3 * 4096 + 64 + N_GRAPHS * F) {
        out[t - (3 * 4096 + 64)] = -INFINITY;
    }
}

// Fused GCN layer (agg-first, barrier-free, padded-CSR, scalar-pipe addressing):
//   g[n] = dis[n]*( hs[n] + sum_{e:dst=n} hs[src] )   (hs pre-scaled by dis; f16 LDS)
//   h'   = relu( g[n]·W + b );  out = bf16( SCALE ? dis*h' : h' )
// Block = 64 nodes, 4 waves; wave owns rows [16w,16w+16) = 4 quads.
// Phase1 per quad: iters = quadslots/16; each iter = one s_load_dwordx16 of 16
// BYTE offsets + 16 gathers whose 64-bit base is formed on the SCALAR pipe
// (uniform offset) with shared voffset lane*2 -> per-edge VALU is just shift+add.
// Sentinel slots point at zero row (L1-hot). No drains, no masks, no barriers.
template<bool RELU, bool SCALE>
__global__ __launch_bounds__(256) void k_layer(const ushort* __restrict__ hs,
                                               const int* __restrict__ qbase,
                                               const int* __restrict__ col,
                                               const float* __restrict__ dis,
                                               const _Float16* __restrict__ Wt,
                                               const float* __restrict__ bias,
                                               ushort* __restrict__ hout) {
    __shared__ _Float16 g[64 * 64];
    int lane = threadIdx.x & 63;
    int w    = __builtin_amdgcn_readfirstlane(threadIdx.x >> 6);
    int chunk = blockIdx.x * 64;
    int wr16 = w * 16;
    int nbase = chunk + wr16;
    const char* hsb = (const char*)hs;
    int l2 = lane << 1;                      // shared per-lane byte offset

    // ---------- phase 1: aggregate 16 nodes (4 quads) ----------
    for (int p = 0; p < 4; ++p) {
        int na = nbase + 4 * p;              // first node of quad
        int quad = na >> 2;
        int rowb = wr16 + 4 * p;
        bool vq = quad < NQUADS;
        int qb0 = 0, iters = 0;
        if (vq) {
            qb0   = __builtin_amdgcn_readfirstlane(qbase[quad]);
            int qb1 = __builtin_amdgcn_readfirstlane(qbase[quad + 1]);
            iters = (qb1 - qb0) >> 4;
        }
        // self-loop init (tail nodes: zero)
        float a0 = vq ? bf2f(hs[(size_t)(na    ) * F + lane]) : 0.f;
        float a1 = vq ? bf2f(hs[(size_t)(na + 1) * F + lane]) : 0.f;
        float a2 = vq ? bf2f(hs[(size_t)(na + 2) * F + lane]) : 0.f;
        float a3 = vq ? bf2f(hs[(size_t)(na + 3) * F + lane]) : 0.f;
        const int* cp0 = col + qb0;
        for (int i = 0; i < iters; ++i) {
            const int* cp = cp0 + (i << 4);  // uniform addr -> s_load_dwordx16
            // scalar-pipe base formation: hsb + uniform byte offset
            float v0  = bf2f(*(const ushort*)(hsb + (uint)cp[0]  + l2));
            float v1  = bf2f(*(const ushort*)(hsb + (uint)cp[1]  + l2));
            float v2  = bf2f(*(const ushort*)(hsb + (uint)cp[2]  + l2));
            float v3  = bf2f(*(const ushort*)(hsb + (uint)cp[3]  + l2));
            float v4  = bf2f(*(const ushort*)(hsb + (uint)cp[4]  + l2));
            float v5  = bf2f(*(const ushort*)(hsb + (uint)cp[5]  + l2));
            float v6  = bf2f(*(const ushort*)(hsb + (uint)cp[6]  + l2));
            float v7  = bf2f(*(const ushort*)(hsb + (uint)cp[7]  + l2));
            float v8  = bf2f(*(const ushort*)(hsb + (uint)cp[8]  + l2));
            float v9  = bf2f(*(const ushort*)(hsb + (uint)cp[9]  + l2));
            float v10 = bf2f(*(const ushort*)(hsb + (uint)cp[10] + l2));
            float v11 = bf2f(*(const ushort*)(hsb + (uint)cp[11] + l2));
            float v12 = bf2f(*(const ushort*)(hsb + (uint)cp[12] + l2));
            float v13 = bf2f(*(const ushort*)(hsb + (uint)cp[13] + l2));
            float v14 = bf2f(*(const ushort*)(hsb + (uint)cp[14] + l2));
            float v15 = bf2f(*(const ushort*)(hsb + (uint)cp[15] + l2));
            a0 += v0 + v4 + v8  + v12;       // interleave: node j at slots j,4+j,8+j,12+j
            a1 += v1 + v5 + v9  + v13;
            a2 += v2 + v6 + v10 + v14;
            a3 += v3 + v7 + v11 + v15;
        }
        // fold dis and store f16 rows (own strip only)
        float d0 = vq ? dis[na]     : 0.f;
        float d1 = vq ? dis[na + 1] : 0.f;
        float d2 = vq ? dis[na + 2] : 0.f;
        float d3 = vq ? dis[na + 3] : 0.f;
        g[(rowb    ) * 64 + lane] = (_Float16)(d0 * a0);
        g[(rowb + 1) * 64 + lane] = (_Float16)(d1 * a1);
        g[(rowb + 2) * 64 + lane] = (_Float16)(d2 * a2);
        g[(rowb + 3) * 64 + lane] = (_Float16)(d3 * a3);
    }
    // no barrier: phase 2 reads only this wave's own strip (same-wave LDS ordering)

    // ---------- phase 2: C[16x64] = g_strip · W via MFMA ----------
    int l15 = lane & 15, lh = lane >> 4;
    half8 bfrag[2][4];
#pragma unroll
    for (int ks = 0; ks < 2; ++ks)
#pragma unroll
        for (int nt = 0; nt < 4; ++nt)
            bfrag[ks][nt] = *(const half8*)(Wt + (nt * 16 + l15) * 64 + ks * 32 + lh * 8);

    f32x4 acc4[4] = {};
#pragma unroll
    for (int ks = 0; ks < 2; ++ks) {
        half8 a = *(const half8*)(&g[(wr16 + l15) * 64 + ks * 32 + lh * 8]);
#pragma unroll
        for (int nt = 0; nt < 4; ++nt)
            acc4[nt] = __builtin_amdgcn_mfma_f32_16x16x32_f16(a, bfrag[ks][nt], acc4[nt], 0, 0, 0);
    }

    // ---------- epilogue: direct global stores (no LDS, no barrier) ----------
    float bvals[4];
#pragma unroll
    for (int nt = 0; nt < 4; ++nt) bvals[nt] = bias[nt * 16 + l15];
#pragma unroll
    for (int rr = 0; rr < 4; ++rr) {
        int row = wr16 + lh * 4 + rr;
        int ng = chunk + row;
        if (ng < N_NODES) {
            float ds2 = 1.f;
            if (SCALE) ds2 = dis[ng];
#pragma unroll
            for (int nt = 0; nt < 4; ++nt) {
                float vv = acc4[nt][rr] + bvals[nt];
                if (RELU) vv = fmaxf(vv, 0.f);
                if (SCALE) vv *= ds2;
                hout[(size_t)ng * F + nt * 16 + l15] = f2bf(vv);
            }
        }
    }
}

__device__ inline void atomicMaxFloat(float* addr, float v) {
    if (v >= 0.f) atomicMax((int*)addr, __float_as_int(v));
    else          atomicMin((unsigned int*)addr, __float_as_uint(v));
}

// batch is sorted: each wave scans a contiguous chunk, flushes on boundary.
__global__ __launch_bounds__(256) void k_pool(const ushort* __restrict__ h,
                                              const int* __restrict__ batch,
                                              float* __restrict__ out) {
    int lane = threadIdx.x & 63;
    int wid  = __builtin_amdgcn_readfirstlane((blockIdx.x * blockDim.x + threadIdx.x) >> 6);
    int nwaves = (gridDim.x * blockDim.x) >> 6;
    int per = (N_NODES + nwaves - 1) / nwaves;
    int n0 = wid * per, n1 = min(N_NODES, n0 + per);
    if (n0 >= n1) return;
    float acc = -INFINITY;
    int cur = batch[n0];
    for (int n = n0; n < n1; ++n) {
        int g = batch[n];
        if (g != cur) {
            atomicMaxFloat(&out[cur * F + lane], acc);
            acc = -INFINITY; cur = g;
        }
        acc = fmaxf(acc, bf2f(h[(size_t)n * F + lane]));
    }
    atomicMaxFloat(&out[cur * F + lane], acc);
}

extern "C" void kernel_launch(void* const* d_in, const int* in_sizes, int n_in,
                              void* d_out, int out_size, void* d_ws, size_t ws_size,
                              hipStream_t stream) {
    const float* x     = (const float*)d_in[0];
    const int*   ei    = (const int*)d_in[1];
    const int*   batch = (const int*)d_in[2];
    const float* W1 = (const float*)d_in[3];
    const float* b1 = (const float*)d_in[4];
    const float* W2 = (const float*)d_in[5];
    const float* b2 = (const float*)d_in[6];
    const float* W3 = (const float*)d_in[7];
    const float* b3 = (const float*)d_in[8];
    const int* src = ei;
    const int* dst = ei + N_EDGES;

    char* ws = (char*)d_ws;
    ushort*   bufA   = (ushort*)(ws + OFF_BUFA);
    int*      rank   = (int*)(ws + OFF_BUFA);     // alias: live only during CSR build
    ushort*   bufB   = (ushort*)(ws + OFF_BUFB);
    float*    dis    = (float*)(ws + OFF_DIS);
    int*      degcnt = (int*)(ws + OFF_DEG);
    int*      qbase  = (int*)(ws + OFF_QB);
    int*      bsum   = (int*)(ws + OFF_BSUM);
    int*      col    = (int*)(ws + OFF_COL);
    _Float16* wt     = (_Float16*)(ws + OFF_WT);
    float*    out    = (float*)d_out;

    // CSR build (quad-padded, interleaved, byte-offset col)
    k_zero<<<(N_NODES + 255) / 256, 256, 0, stream>>>(degcnt, N_NODES);
    k_degree<<<(N_EDGES + 255) / 256, 256, 0, stream>>>(dst, degcnt, rank);
    k_quad<<<25, 1024, 0, stream>>>(degcnt, qbase, bsum, dis);
    k_scan2<<<1, 128, 0, stream>>>(bsum, 25);
    k_scan3<<<25, 1024, 0, stream>>>(qbase, bsum);
    k_colinit<<<1024, 256, 0, stream>>>(qbase, col);
    k_fill<<<(N_EDGES + 255) / 256, 256, 0, stream>>>(src, dst, qbase, rank, col);

    // prep: xs = bf16(dis*x) (overwrites rank region); Wt + sentinels + pool-init
    k_prepx<<<(N_NODES * 8 + 255) / 256, 256, 0, stream>>>(x, dis, bufA);
    k_prepw<<<65, 256, 0, stream>>>(W1, W2, W3, wt, bufA, bufB, out);

    const int LBLOCKS = (N_NODES + 63) / 64;   // 1563
    k_layer<true,  true ><<<LBLOCKS, 256, 0, stream>>>(bufA, qbase, col, dis, wt,        b1, bufB);
    k_layer<true,  true ><<<LBLOCKS, 256, 0, stream>>>(bufB, qbase, col, dis, wt + 4096, b2, bufA);
    k_layer<false, false><<<LBLOCKS, 256, 0, stream>>>(bufA, qbase, col, dis, wt + 8192, b3, bufB);

    // global max pool
    k_pool<<<512, 256, 0, stream>>>(bufB, batch, out);
}

// Round 13
// 157.240 us; speedup vs baseline: 1.4258x; 1.1519x over previous
//
#include <hip/hip_runtime.h>
#include <math.h>

#define N_NODES  100000
#define N_EDGES  800000
#define F        64
#define N_GRAPHS 64
#define NQUADS   25000       // N_NODES/4 exactly
#define ROWB     128         // bytes per hs row (64 * bf16)
#define COLCAP   3500000     // col slots; bound: 4*sum(maxdeg)+12/quad <= 3.5M
#define SENT     (N_NODES * ROWB)

typedef _Float16 half8 __attribute__((ext_vector_type(8)));
typedef float    f32x4 __attribute__((ext_vector_type(4)));

// ---------------- workspace layout (bytes) ----------------
#define OFF_BUFA 0u           // ushort[(N+1)*F] 12,800,128 (row N = zero sentinel)
#define OFF_BUFB 12800256u    // ushort[(N+1)*F] 12,800,128
#define OFF_DIS  25600512u    // float[N]       400,000
#define OFF_DEG  26000512u    // int[N]         400,000
#define OFF_QB   26400512u    // int[NQUADS+1]  100,004
#define OFF_BSUM 26500544u    // int[128]
#define OFF_COL  26501120u    // int[3.5M]   14,000,000 (padded+interleaved BYTE offsets)
#define OFF_WT   40501120u    // _Float16[3*4096] 24,576
#define OFF_RANK 40525696u    // int[E]       3,200,000
// total ~43.7 MB

__device__ inline ushort f2bf(float f) {               // round-to-nearest-even
    uint u = __float_as_uint(f);
    u = (u + 0x7FFFu + ((u >> 16) & 1u)) >> 16;
    return (ushort)u;
}
__device__ inline float bf2f(ushort s) {
    return __uint_as_float(((uint)s) << 16);
}

__device__ inline void atomicMaxFloat(float* addr, float v) {
    if (v >= 0.f) atomicMax((int*)addr, __float_as_int(v));
    else          atomicMin((unsigned int*)addr, __float_as_uint(v));
}

// One dependency-free init kernel: sentinel whole col region, zero degcnt,
// build f16 transposed weights, zero hs sentinel rows, init pool output.
__global__ void k_init(const float* __restrict__ W1, const float* __restrict__ W2,
                       const float* __restrict__ W3, _Float16* __restrict__ Wt,
                       ushort* __restrict__ bufA, ushort* __restrict__ bufB,
                       float* __restrict__ out, int* __restrict__ degcnt,
                       int* __restrict__ col) {
    int tid = blockIdx.x * blockDim.x + threadIdx.x;
    int stride = gridDim.x * blockDim.x;
    for (int i = tid; i < COLCAP; i += stride) col[i] = SENT;
    for (int i = tid; i < N_NODES; i += stride) degcnt[i] = 0;
    if (tid < 3 * 4096) {
        int wsel = tid >> 12, i = tid & 4095;
        int k = i >> 6, f = i & 63;
        const float* Ws = (wsel == 0) ? W1 : (wsel == 1) ? W2 : W3;
        Wt[wsel * 4096 + f * 64 + k] = (_Float16)Ws[k * 64 + f];
    } else if (tid < 3 * 4096 + 64) {
        int f = tid - 3 * 4096;
        bufA[(size_t)N_NODES * F + f] = 0;
        bufB[(size_t)N_NODES * F + f] = 0;
    } else if (tid < 3 * 4096 + 64 + N_GRAPHS * F) {
        out[tid - (3 * 4096 + 64)] = -INFINITY;
    }
}

// degree count AND per-edge rank (return value of the atomic we already pay)
__global__ void k_degree(const int* __restrict__ dst, int* __restrict__ degcnt,
                         int* __restrict__ rank) {
    int e = blockIdx.x * blockDim.x + threadIdx.x;
    if (e < N_EDGES) rank[e] = atomicAdd(&degcnt[dst[e]], 1);
}

// per-QUAD: dis for 4 nodes; padded quad slots = 4*ceil(maxdeg/4) (rounded up x4);
// block-inclusive-scan -> qbase[q+1]; block totals -> bsum.
__global__ void k_quad(const int* __restrict__ degcnt, int* __restrict__ qbase,
                       int* __restrict__ bsum, float* __restrict__ dis) {
    __shared__ int s[1024];
    int q = blockIdx.x * 1024 + threadIdx.x;
    int tot = 0;
    if (q < NQUADS) {
        const int4 d4 = *(const int4*)(degcnt + q * 4);
        float4 dv;
        dv.x = rsqrtf((float)d4.x + 1.0f);
        dv.y = rsqrtf((float)d4.y + 1.0f);
        dv.z = rsqrtf((float)d4.z + 1.0f);
        dv.w = rsqrtf((float)d4.w + 1.0f);
        *(float4*)(dis + q * 4) = dv;
        int m = max(max(d4.x, d4.y), max(d4.z, d4.w));
        int P = (m + 3) & ~3;          // per-node padded length (multiple of 4)
        tot = 4 * P;                   // quad slots (multiple of 16)
    }
    s[threadIdx.x] = tot;
    __syncthreads();
    for (int off = 1; off < 1024; off <<= 1) {
        int t = (threadIdx.x >= off) ? s[threadIdx.x - off] : 0;
        __syncthreads();
        s[threadIdx.x] += t;
        __syncthreads();
    }
    if (q < NQUADS) qbase[q + 1] = s[threadIdx.x];
    if (threadIdx.x == 1023) bsum[blockIdx.x] = s[1023];
}

// merged: blocks 0..24 finish the qbase scan (each computes its own bsum prefix);
// blocks 25+ run prepx: xs = bf16(dis * x)  (needs only dis, from k_quad).
__global__ void k_scan3px(int* __restrict__ qbase, const int* __restrict__ bsum,
                          const float* __restrict__ x, const float* __restrict__ dis,
                          ushort* __restrict__ xs) {
    if (blockIdx.x < 25) {
        __shared__ int soff;
        if (threadIdx.x == 0) {
            int acc = 0;
            for (int j = 0; j < (int)blockIdx.x; ++j) acc += bsum[j];
            soff = acc;
        }
        __syncthreads();
        int off = soff;
        int q = blockIdx.x * 1024 + threadIdx.x;
        if (q < NQUADS) qbase[q + 1] += off;
        if (q == 0) qbase[0] = 0;
    } else {
        int t = (blockIdx.x - 25) * 1024 + threadIdx.x;
        if (t < N_NODES * 8) {
            int n = t >> 3;
            float d = dis[n];
            const float4* px = (const float4*)(x + (size_t)t * 8);
            float4 a = px[0], b = px[1];
            ushort o[8] = { f2bf(d*a.x), f2bf(d*a.y), f2bf(d*a.z), f2bf(d*a.w),
                            f2bf(d*b.x), f2bf(d*b.y), f2bf(d*b.z), f2bf(d*b.w) };
            *(uint4*)(xs + (size_t)t * 8) = *(const uint4*)o;
        }
    }
}

// interleaved padded fill with BYTE offsets:
// edge (src,dst,rank) -> col[qbase[dst/4] + rank*4 + (dst&3)] = src*ROWB
__global__ void k_fill(const int* __restrict__ src, const int* __restrict__ dst,
                       const int* __restrict__ qbase, const int* __restrict__ rank,
                       int* __restrict__ col) {
    int e = blockIdx.x * blockDim.x + threadIdx.x;
    if (e < N_EDGES) {
        int d = dst[e];
        col[qbase[d >> 2] + rank[e] * 4 + (d & 3)] = src[e] * ROWB;
    }
}

// Fused GCN layer (agg-first, padded-CSR, scalar-pipe addressing):
//   g[n] = dis[n]*( hs[n] + sum_{e:dst=n} hs[src] )   (hs pre-scaled by dis; f16 LDS)
//   h'   = relu( g[n]·W + b )
//   POOL=false: out = bf16( SCALE ? dis*h' : h' ) -> hout
//   POOL=true : global-max-pool h' into out[graph][f] (batch sorted; LDS tile
//               pl[4][64] for graphs gmin..gmin+3, int-trick LDS atomics; rare
//               rel>=4 falls back to direct global atomicMaxFloat). No h write.
// Block = 64 nodes, 4 waves; wave owns rows [16w,16w+16) = 4 quads; phase 1/2
// barrier-free (wave-private LDS strip); POOL adds one barrier pair at the end.
template<bool RELU, bool SCALE, bool POOL>
__global__ __launch_bounds__(256) void k_layer(const ushort* __restrict__ hs,
                                               const int* __restrict__ qbase,
                                               const int* __restrict__ col,
                                               const float* __restrict__ dis,
                                               const _Float16* __restrict__ Wt,
                                               const float* __restrict__ bias,
                                               ushort* __restrict__ hout,
                                               const int* __restrict__ batch,
                                               float* __restrict__ out) {
    __shared__ _Float16 g[64 * 64];
    __shared__ float pl[4 * 64];
    int lane = threadIdx.x & 63;
    int w    = __builtin_amdgcn_readfirstlane(threadIdx.x >> 6);
    int chunk = blockIdx.x * 64;
    int wr16 = w * 16;
    int nbase = chunk + wr16;
    const char* hsb = (const char*)hs;
    int l2 = lane << 1;                      // shared per-lane byte offset

    if (POOL) pl[threadIdx.x] = -INFINITY;

    // ---------- phase 1: aggregate 16 nodes (4 quads) ----------
    for (int p = 0; p < 4; ++p) {
        int na = nbase + 4 * p;              // first node of quad
        int quad = na >> 2;
        int rowb = wr16 + 4 * p;
        bool vq = quad < NQUADS;
        int qb0 = 0, iters = 0;
        if (vq) {
            qb0   = __builtin_amdgcn_readfirstlane(qbase[quad]);
            int qb1 = __builtin_amdgcn_readfirstlane(qbase[quad + 1]);
            iters = (qb1 - qb0) >> 4;
        }
        float a0 = vq ? bf2f(hs[(size_t)(na    ) * F + lane]) : 0.f;
        float a1 = vq ? bf2f(hs[(size_t)(na + 1) * F + lane]) : 0.f;
        float a2 = vq ? bf2f(hs[(size_t)(na + 2) * F + lane]) : 0.f;
        float a3 = vq ? bf2f(hs[(size_t)(na + 3) * F + lane]) : 0.f;
        const int* cp0 = col + qb0;
        for (int i = 0; i < iters; ++i) {
            const int* cp = cp0 + (i << 4);  // uniform addr -> s_load_dwordx16
            float v0  = bf2f(*(const ushort*)(hsb + (uint)cp[0]  + l2));
            float v1  = bf2f(*(const ushort*)(hsb + (uint)cp[1]  + l2));
            float v2  = bf2f(*(const ushort*)(hsb + (uint)cp[2]  + l2));
            float v3  = bf2f(*(const ushort*)(hsb + (uint)cp[3]  + l2));
            float v4  = bf2f(*(const ushort*)(hsb + (uint)cp[4]  + l2));
            float v5  = bf2f(*(const ushort*)(hsb + (uint)cp[5]  + l2));
            float v6  = bf2f(*(const ushort*)(hsb + (uint)cp[6]  + l2));
            float v7  = bf2f(*(const ushort*)(hsb + (uint)cp[7]  + l2));
            float v8  = bf2f(*(const ushort*)(hsb + (uint)cp[8]  + l2));
            float v9  = bf2f(*(const ushort*)(hsb + (uint)cp[9]  + l2));
            float v10 = bf2f(*(const ushort*)(hsb + (uint)cp[10] + l2));
            float v11 = bf2f(*(const ushort*)(hsb + (uint)cp[11] + l2));
            float v12 = bf2f(*(const ushort*)(hsb + (uint)cp[12] + l2));
            float v13 = bf2f(*(const ushort*)(hsb + (uint)cp[13] + l2));
            float v14 = bf2f(*(const ushort*)(hsb + (uint)cp[14] + l2));
            float v15 = bf2f(*(const ushort*)(hsb + (uint)cp[15] + l2));
            a0 += v0 + v4 + v8  + v12;       // interleave: node j at slots j,4+j,8+j,12+j
            a1 += v1 + v5 + v9  + v13;
            a2 += v2 + v6 + v10 + v14;
            a3 += v3 + v7 + v11 + v15;
        }
        float d0 = vq ? dis[na]     : 0.f;
        float d1 = vq ? dis[na + 1] : 0.f;
        float d2 = vq ? dis[na + 2] : 0.f;
        float d3 = vq ? dis[na + 3] : 0.f;
        g[(rowb    ) * 64 + lane] = (_Float16)(d0 * a0);
        g[(rowb + 1) * 64 + lane] = (_Float16)(d1 * a1);
        g[(rowb + 2) * 64 + lane] = (_Float16)(d2 * a2);
        g[(rowb + 3) * 64 + lane] = (_Float16)(d3 * a3);
    }
    // no barrier: phase 2 reads only this wave's own strip (same-wave LDS ordering)

    // ---------- phase 2: C[16x64] = g_strip · W via MFMA ----------
    int l15 = lane & 15, lh = lane >> 4;
    half8 bfrag[2][4];
#pragma unroll
    for (int ks = 0; ks < 2; ++ks)
#pragma unroll
        for (int nt = 0; nt < 4; ++nt)
            bfrag[ks][nt] = *(const half8*)(Wt + (nt * 16 + l15) * 64 + ks * 32 + lh * 8);

    f32x4 acc4[4] = {};
#pragma unroll
    for (int ks = 0; ks < 2; ++ks) {
        half8 a = *(const half8*)(&g[(wr16 + l15) * 64 + ks * 32 + lh * 8]);
#pragma unroll
        for (int nt = 0; nt < 4; ++nt)
            acc4[nt] = __builtin_amdgcn_mfma_f32_16x16x32_f16(a, bfrag[ks][nt], acc4[nt], 0, 0, 0);
    }

    // ---------- epilogue ----------
    float bvals[4];
#pragma unroll
    for (int nt = 0; nt < 4; ++nt) bvals[nt] = bias[nt * 16 + l15];

    if (POOL) __syncthreads();   // pl init + all waves ready before LDS atomics
    int gmin = 0;
    if (POOL) gmin = __builtin_amdgcn_readfirstlane(batch[chunk]);

#pragma unroll
    for (int rr = 0; rr < 4; ++rr) {
        int row = wr16 + lh * 4 + rr;
        int ng = chunk + row;
        if (ng < N_NODES) {
            if (POOL) {
                int gb = batch[ng];
                int rel = gb - gmin;
#pragma unroll
                for (int nt = 0; nt < 4; ++nt) {
                    float vv = acc4[nt][rr] + bvals[nt];
                    if (RELU) vv = fmaxf(vv, 0.f);
                    if (rel < 4) atomicMaxFloat(&pl[rel * 64 + nt * 16 + l15], vv);
                    else         atomicMaxFloat(&out[gb * F + nt * 16 + l15], vv);
                }
            } else {
                float ds2 = 1.f;
                if (SCALE) ds2 = dis[ng];
#pragma unroll
                for (int nt = 0; nt < 4; ++nt) {
                    float vv = acc4[nt][rr] + bvals[nt];
                    if (RELU) vv = fmaxf(vv, 0.f);
                    if (SCALE) vv *= ds2;
                    hout[(size_t)ng * F + nt * 16 + l15] = f2bf(vv);
                }
            }
        }
    }
    if (POOL) {
        __syncthreads();
        float v = pl[threadIdx.x];
        int r = threadIdx.x >> 6, c = threadIdx.x & 63;
        int gg = gmin + r;
        if (v != -INFINITY && gg < N_GRAPHS)
            atomicMaxFloat(&out[gg * F + c], v);
    }
}

extern "C" void kernel_launch(void* const* d_in, const int* in_sizes, int n_in,
                              void* d_out, int out_size, void* d_ws, size_t ws_size,
                              hipStream_t stream) {
    const float* x     = (const float*)d_in[0];
    const int*   ei    = (const int*)d_in[1];
    const int*   batch = (const int*)d_in[2];
    const float* W1 = (const float*)d_in[3];
    const float* b1 = (const float*)d_in[4];
    const float* W2 = (const float*)d_in[5];
    const float* b2 = (const float*)d_in[6];
    const float* W3 = (const float*)d_in[7];
    const float* b3 = (const float*)d_in[8];
    const int* src = ei;
    const int* dst = ei + N_EDGES;

    char* ws = (char*)d_ws;
    ushort*   bufA   = (ushort*)(ws + OFF_BUFA);
    ushort*   bufB   = (ushort*)(ws + OFF_BUFB);
    float*    dis    = (float*)(ws + OFF_DIS);
    int*      degcnt = (int*)(ws + OFF_DEG);
    int*      qbase  = (int*)(ws + OFF_QB);
    int*      bsum   = (int*)(ws + OFF_BSUM);
    int*      col    = (int*)(ws + OFF_COL);
    _Float16* wt     = (_Float16*)(ws + OFF_WT);
    int*      rank   = (int*)(ws + OFF_RANK);
    float*    out    = (float*)d_out;

    // 1) dependency-free init (col sentinels, degcnt zero, Wt, hs sentinel rows, out=-INF)
    k_init<<<1024, 256, 0, stream>>>(W1, W2, W3, wt, bufA, bufB, out, degcnt, col);
    // 2) degree + rank
    k_degree<<<(N_EDGES + 255) / 256, 256, 0, stream>>>(dst, degcnt, rank);
    // 3) quad-padded sizes + dis + block scan
    k_quad<<<25, 1024, 0, stream>>>(degcnt, qbase, bsum, dis);
    // 4) finish scan (blocks 0..24) || prepx (blocks 25+)
    k_scan3px<<<25 + (N_NODES * 8 + 1023) / 1024, 1024, 0, stream>>>(qbase, bsum, x, dis, bufA);
    // 5) interleaved padded fill (byte offsets)
    k_fill<<<(N_EDGES + 255) / 256, 256, 0, stream>>>(src, dst, qbase, rank, col);

    const int LBLOCKS = (N_NODES + 63) / 64;   // 1563
    k_layer<true,  true,  false><<<LBLOCKS, 256, 0, stream>>>(bufA, qbase, col, dis, wt,        b1, bufB, nullptr, nullptr);
    k_layer<true,  true,  false><<<LBLOCKS, 256, 0, stream>>>(bufB, qbase, col, dis, wt + 4096, b2, bufA, nullptr, nullptr);
    k_layer<false, false, true ><<<LBLOCKS, 256, 0, stream>>>(bufA, qbase, col, dis, wt + 8192, b3, bufB, batch, out);
}